// Round 2
// baseline (589.373 us; speedup 1.0000x reference)
//
#include <hip/hip_runtime.h>
#include <hip/hip_bf16.h>
#include <math.h>

typedef __attribute__((ext_vector_type(4))) float  f32x4;
typedef __attribute__((ext_vector_type(8))) __bf16 bf16x8;
typedef __attribute__((ext_vector_type(4))) unsigned int u32x4;

__device__ __forceinline__ unsigned short f2bu(float x) {
    __bf16 h = (__bf16)x;
    return __builtin_bit_cast(unsigned short, h);
}

__device__ __forceinline__ f32x4 MF(bf16x8 a, bf16x8 b, f32x4 c) {
    return __builtin_amdgcn_mfma_f32_16x16x32_bf16(a, b, c, 0, 0, 0);
}

__device__ __forceinline__ f32x4 zero4() { f32x4 z = {0.f, 0.f, 0.f, 0.f}; return z; }

// B-fragment (BT row-major, contiguous K): lane holds BT[row][k0..k0+7], f32 -> bf16
__device__ __forceinline__ bf16x8 bfrag_g(const float* W, int ldk, int row, int k0) {
    const float* p = W + (size_t)row * ldk + k0;
    bf16x8 r;
#pragma unroll
    for (int e = 0; e < 8; ++e) r[e] = (__bf16)p[e];
    return r;
}

// LDS layout (bytes) -- M=32 atoms per tile
#define VIN_OFF 0        // 3 * 32 rows * 256B (bf16[32][128] per d) = 24576
#define H_OFF   24576    // 32 rows * 512B (bf16[32][256])           = 16384
#define S1_OFF  40960    // 32 rows * 256B                           = 8192
#define RED_OFF 49152    // 8 waves * 32 f32                         = 1024
#define LDS_BYTES 50176

// A-fragment read from swizzled LDS tile
__device__ __forceinline__ bf16x8 afrag(const unsigned char* base, int rb, int row, int kb) {
    u32x4 q = *(const u32x4*)(base + row * rb + (kb ^ ((row & 7) << 4)));
    return __builtin_bit_cast(bf16x8, q);
}

__device__ __forceinline__ unsigned long long pack4bf(f32x4 x) {
    return (unsigned long long)f2bu(x[0])
         | ((unsigned long long)f2bu(x[1]) << 16)
         | ((unsigned long long)f2bu(x[2]) << 32)
         | ((unsigned long long)f2bu(x[3]) << 48);
}

// ---- next-tile staging helpers (M=32): V tile = 3072 f32x4, S tile = 1024 f32x4 ----
__device__ __forceinline__ void issue_loads(const float* __restrict__ S,
                                            const float* __restrict__ V,
                                            int a0, int tid, f32x4* vld, f32x4* sld) {
#pragma unroll
    for (int i = 0; i < 6; ++i) {
        int c = tid + (i << 9);
        int row = c / 96, rem = c - row * 96;
        int d = rem >> 5, c4 = rem & 31;
        vld[i] = *(const f32x4*)(V + (((size_t)(a0 + row) * 3 + d) << 7) + (c4 << 2));
    }
#pragma unroll
    for (int i = 0; i < 2; ++i) {
        int c = tid + (i << 9);
        int row = c >> 5, c4 = c & 31;
        sld[i] = *(const f32x4*)(S + (((size_t)(a0 + row)) << 7) + (c4 << 2));
    }
}

__device__ __forceinline__ void write_V(unsigned char* lds, int tid, const f32x4* vld) {
#pragma unroll
    for (int i = 0; i < 6; ++i) {
        int c = tid + (i << 9);
        int row = c / 96, rem = c - row * 96;
        int d = rem >> 5, c4 = rem & 31;
        *(unsigned long long*)(lds + VIN_OFF + (d << 13) + row * 256 +
                               ((c4 << 3) ^ ((row & 7) << 4))) = pack4bf(vld[i]);
    }
}

__device__ __forceinline__ void write_S(unsigned char* lds, int tid, const f32x4* sld) {
#pragma unroll
    for (int i = 0; i < 2; ++i) {
        int c = tid + (i << 9);
        int row = c >> 5, c4 = c & 31;
        *(unsigned long long*)(lds + H_OFF + row * 512 +
                               ((c4 << 3) ^ ((row & 7) << 4))) = pack4bf(sld[i]);
    }
}

__global__ __launch_bounds__(512, 2) void eqsc_main(
    const float* __restrict__ S, const float* __restrict__ V,
    const float* __restrict__ u0w, const float* __restrict__ v0w,
    const float* __restrict__ a0w1, const float* __restrict__ a0b1,
    const float* __restrict__ a0w2, const float* __restrict__ a0b2,
    const float* __restrict__ u1w, const float* __restrict__ v1w,
    const float* __restrict__ a1w1, const float* __restrict__ a1b1,
    const float* __restrict__ a1w2, const float* __restrict__ a1b2,
    const float* __restrict__ outw, const float* __restrict__ outbp,
    float* __restrict__ sOut, int NT)
{
    __shared__ __align__(16) unsigned char lds[LDS_BYTES];
    const int tid  = threadIdx.x;
    const int lane = tid & 63;
    const int wv   = tid >> 6;
    const int l15  = lane & 15;
    const int lg   = lane >> 4;
    const int grow = wv * 16 + l15;   // this wave/lane's output feature column
    const int kbb  = lg << 4;         // k-byte base within a 64B kt chunk

    // ---- persistent weight fragments (bf16, register-resident) ----
    bf16x8 uw0f[4], vw0f[4], w2g0[4], w2s0[4], vw1f[4], w2g1[4];
    bf16x8 w1f0[8], w1f1[8];
#pragma unroll
    for (int kt = 0; kt < 4; ++kt) {
        int k0 = kt * 32 + lg * 8;
        uw0f[kt] = bfrag_g(u0w, 128, grow, k0);
        vw0f[kt] = bfrag_g(v0w, 128, grow, k0);
        w2g0[kt] = bfrag_g(a0w2, 128, grow, k0);
        w2s0[kt] = bfrag_g(a0w2, 128, 128 + grow, k0);
        vw1f[kt] = bfrag_g(v1w, 128, grow, k0);
        w2g1[kt] = bfrag_g(a1w2, 128, grow, k0);
    }
#pragma unroll
    for (int kt = 0; kt < 8; ++kt) {
        int k0 = kt * 32 + lg * 8;
        w1f0[kt] = bfrag_g(a0w1, 256, grow, k0);
        w1f1[kt] = bfrag_g(a1w1, 256, grow, k0);
    }
    const float b1_0 = a0b1[grow];
    const float b2g0 = a0b2[grow];
    const float b2s0 = a0b2[128 + grow];
    const float b1_1 = a1b1[grow];
    const float b2g1 = a1b2[grow];
    const float owv  = outw[grow];
    const float outb = outbp[0];

    const int stride = gridDim.x;
    int t0 = blockIdx.x;

    // ---- prologue: stage tile t0 ----
    if (t0 < NT) {
        f32x4 vld[6], sld[2];
        issue_loads(S, V, t0 << 5, tid, vld, sld);
        write_V(lds, tid, vld);
        write_S(lds, tid, sld);
    }
    __syncthreads();

    for (int t = t0; t < NT; t += stride) {
        const int a0 = t << 5;
        const int tn = t + stride;

        // ---- P1: L0 v-phase: v1 (kept in regs), v2 -> norm ----
        f32x4 v1a[2][3];
#pragma unroll
        for (int m = 0; m < 2; ++m) {
            f32x4 n2 = zero4();
#pragma unroll
            for (int d = 0; d < 3; ++d) {
                f32x4 acc1 = zero4(), acc2 = zero4();
#pragma unroll
                for (int kt = 0; kt < 4; ++kt) {
                    bf16x8 a = afrag(lds + VIN_OFF + (d << 13), 256, (m << 4) + l15, (kt << 6) + kbb);
                    acc1 = MF(a, uw0f[kt], acc1);
                    acc2 = MF(a, vw0f[kt], acc2);
                }
                v1a[m][d] = acc1;
#pragma unroll
                for (int e = 0; e < 4; ++e) { float x = acc2[e] + 1e-8f; n2[e] += x * x; }
            }
#pragma unroll
            for (int e = 0; e < 4; ++e) {
                int row = (m << 4) + (lg << 2) + e;
                *(unsigned short*)(lds + H_OFF + row * 512 +
                    ((256 + (grow << 1)) ^ ((row & 7) << 4))) = f2bu(sqrtf(n2[e]));
            }
        }
        __syncthreads();

        // ---- P2: L0 MLP1 (K=256 -> 128, silu) -- two interleaved acc chains ----
        {
            f32x4 ma = zero4(), mb = zero4();
#pragma unroll
            for (int kt = 0; kt < 8; ++kt) {
                bf16x8 af0 = afrag(lds + H_OFF, 512, l15,      (kt << 6) + kbb);
                bf16x8 af1 = afrag(lds + H_OFF, 512, 16 + l15, (kt << 6) + kbb);
                ma = MF(af0, w1f0[kt], ma);
                mb = MF(af1, w1f0[kt], mb);
            }
#pragma unroll
            for (int e = 0; e < 4; ++e) {
                { float x = ma[e] + b1_0; float y = x / (1.f + __expf(-x));
                  int row = (lg << 2) + e;
                  *(unsigned short*)(lds + S1_OFF + row * 256 +
                      ((grow << 1) ^ ((row & 7) << 4))) = f2bu(y); }
                { float x = mb[e] + b1_0; float y = x / (1.f + __expf(-x));
                  int row = 16 + (lg << 2) + e;
                  *(unsigned short*)(lds + S1_OFF + row * 256 +
                      ((grow << 1) ^ ((row & 7) << 4))) = f2bu(y); }
            }
        }
        __syncthreads();

        // ---- P3: L0 MLP2 (sg | ss); s' -> H[:,0:128]; v' = v1*ss -> VIN (V dead) ----
#pragma unroll
        for (int m = 0; m < 2; ++m) {
            f32x4 sg = zero4(), ssa = zero4();
#pragma unroll
            for (int kt = 0; kt < 4; ++kt) {
                bf16x8 a = afrag(lds + S1_OFF, 256, (m << 4) + l15, (kt << 6) + kbb);
                sg  = MF(a, w2g0[kt], sg);
                ssa = MF(a, w2s0[kt], ssa);
            }
#pragma unroll
            for (int e = 0; e < 4; ++e) {
                int row = (m << 4) + (lg << 2) + e;
                int swz = (row & 7) << 4;
                *(unsigned short*)(lds + H_OFF + row * 512 + ((grow << 1) ^ swz)) = f2bu(sg[e] + b2g0);
                float ssv = ssa[e] + b2s0;
#pragma unroll
                for (int d = 0; d < 3; ++d)
                    *(unsigned short*)(lds + VIN_OFF + (d << 13) + row * 256 +
                        ((grow << 1) ^ swz)) = f2bu(v1a[m][d][e] * ssv);
            }
        }
        __syncthreads();

        // ---- P4: L1 v-phase (v2 only; L1 v1 is dead code); issue next-tile loads ----
        f32x4 vld[6], sld[2];
        if (tn < NT) issue_loads(S, V, tn << 5, tid, vld, sld);
#pragma unroll
        for (int m = 0; m < 2; ++m) {
            f32x4 n2 = zero4();
#pragma unroll
            for (int d = 0; d < 3; ++d) {
                f32x4 acc = zero4();
#pragma unroll
                for (int kt = 0; kt < 4; ++kt)
                    acc = MF(afrag(lds + VIN_OFF + (d << 13), 256, (m << 4) + l15, (kt << 6) + kbb),
                             vw1f[kt], acc);
#pragma unroll
                for (int e = 0; e < 4; ++e) { float x = acc[e] + 1e-8f; n2[e] += x * x; }
            }
#pragma unroll
            for (int e = 0; e < 4; ++e) {
                int row = (m << 4) + (lg << 2) + e;
                *(unsigned short*)(lds + H_OFF + row * 512 +
                    ((256 + (grow << 1)) ^ ((row & 7) << 4))) = f2bu(sqrtf(n2[e]));
            }
        }
        __syncthreads();

        // ---- P5: L1 MLP1; then stage V(t+1) into VIN (v' dead after P4) ----
        {
            f32x4 ma = zero4(), mb = zero4();
#pragma unroll
            for (int kt = 0; kt < 8; ++kt) {
                bf16x8 af0 = afrag(lds + H_OFF, 512, l15,      (kt << 6) + kbb);
                bf16x8 af1 = afrag(lds + H_OFF, 512, 16 + l15, (kt << 6) + kbb);
                ma = MF(af0, w1f1[kt], ma);
                mb = MF(af1, w1f1[kt], mb);
            }
#pragma unroll
            for (int e = 0; e < 4; ++e) {
                { float x = ma[e] + b1_1; float y = x / (1.f + __expf(-x));
                  int row = (lg << 2) + e;
                  *(unsigned short*)(lds + S1_OFF + row * 256 +
                      ((grow << 1) ^ ((row & 7) << 4))) = f2bu(y); }
                { float x = mb[e] + b1_1; float y = x / (1.f + __expf(-x));
                  int row = 16 + (lg << 2) + e;
                  *(unsigned short*)(lds + S1_OFF + row * 256 +
                      ((grow << 1) ^ ((row & 7) << 4))) = f2bu(y); }
            }
        }
        if (tn < NT) write_V(lds, tid, vld);
        __syncthreads();

        // ---- P6: L1 MLP2 (gate half) + readout + per-wave reduce; stage S(t+1) ----
#pragma unroll
        for (int m = 0; m < 2; ++m) {
            f32x4 sg = zero4();
#pragma unroll
            for (int kt = 0; kt < 4; ++kt)
                sg = MF(afrag(lds + S1_OFF, 256, (m << 4) + l15, (kt << 6) + kbb), w2g1[kt], sg);
            float p[4];
#pragma unroll
            for (int e = 0; e < 4; ++e) p[e] = (sg[e] + b2g1) * owv;
#pragma unroll
            for (int off = 1; off < 16; off <<= 1) {
#pragma unroll
                for (int e = 0; e < 4; ++e) p[e] += __shfl_xor(p[e], off);
            }
            if (l15 == 0) {
#pragma unroll
                for (int e = 0; e < 4; ++e)
                    *((float*)(lds + RED_OFF) + (wv << 5) + (m << 4) + (lg << 2) + e) = p[e];
            }
        }
        if (tn < NT) write_S(lds, tid, sld);
        __syncthreads();

        if (tid < 32) {
            float s = 0.f;
#pragma unroll
            for (int w = 0; w < 8; ++w) s += *((float*)(lds + RED_OFF) + (w << 5) + tid);
            sOut[a0 + tid] = s + outb;
        }
        // no barrier needed: next-iter P1 reads VIN (staged pre-P5-barrier) and
        // P2 reads H s (staged pre-P6-barrier); RED not touched until next P6.
    }
}

// Dense masked pooling: y[b] = sum_a batch[b,a] * s_out[a]
__global__ __launch_bounds__(256) void eqsc_pool(const float* __restrict__ batch,
                                                 const float* __restrict__ s,
                                                 float* __restrict__ out,
                                                 int NA, int B, int CH)
{
    int b  = blockIdx.x % B;
    int ch = blockIdx.x / B;
    int a0 = ch * CH;
    int a1 = min(a0 + CH, NA);
    const float* br = batch + (size_t)b * NA;
    float acc = 0.f;
    for (int a = a0 + (threadIdx.x << 2); a < a1; a += 256 * 4) {
        f32x4 bb = *(const f32x4*)(br + a);
        f32x4 sv = *(const f32x4*)(s + a);
        acc += bb[0] * sv[0] + bb[1] * sv[1] + bb[2] * sv[2] + bb[3] * sv[3];
    }
#pragma unroll
    for (int off = 32; off > 0; off >>= 1) acc += __shfl_down(acc, off);
    __shared__ float wsum[4];
    if ((threadIdx.x & 63) == 0) wsum[threadIdx.x >> 6] = acc;
    __syncthreads();
    if (threadIdx.x == 0) atomicAdd(&out[b], wsum[0] + wsum[1] + wsum[2] + wsum[3]);
}

extern "C" void kernel_launch(void* const* d_in, const int* in_sizes, int n_in,
                              void* d_out, int out_size, void* d_ws, size_t ws_size,
                              hipStream_t stream)
{
    const float* S     = (const float*)d_in[0];
    const float* V     = (const float*)d_in[1];
    // d_in[2] = pos, unused by the reference
    const float* batch = (const float*)d_in[3];
    const float* u0w   = (const float*)d_in[4];
    const float* v0w   = (const float*)d_in[5];
    const float* a0w1  = (const float*)d_in[6];
    const float* a0b1  = (const float*)d_in[7];
    const float* a0w2  = (const float*)d_in[8];
    const float* a0b2  = (const float*)d_in[9];
    const float* u1w   = (const float*)d_in[10];
    const float* v1w   = (const float*)d_in[11];
    const float* a1w1  = (const float*)d_in[12];
    const float* a1b1  = (const float*)d_in[13];
    const float* a1w2  = (const float*)d_in[14];
    const float* a1b2  = (const float*)d_in[15];
    const float* outw  = (const float*)d_in[16];
    const float* outb  = (const float*)d_in[17];

    const int NA = in_sizes[0] / 128;
    const int NT = NA / 32;                  // 32 atoms per tile
    const int B  = in_sizes[3] / NA;
    float* sAtom = (float*)d_ws;

    hipMemsetAsync(d_out, 0, (size_t)out_size * sizeof(float), stream);

    eqsc_main<<<256, 512, 0, stream>>>(S, V, u0w, v0w, a0w1, a0b1, a0w2, a0b2,
                                       u1w, v1w, a1w1, a1b1, a1w2, a1b2,
                                       outw, outb, sAtom, NT);

    const int CH  = 16384;
    const int NCH = (NA + CH - 1) / CH;
    eqsc_pool<<<B * NCH, 256, 0, stream>>>(batch, sAtom, (float*)d_out, NA, B, CH);
}

// Round 3
// 276.732 us; speedup vs baseline: 2.1298x; 2.1298x over previous
//
#include <hip/hip_runtime.h>
#include <hip/hip_bf16.h>
#include <math.h>

typedef __attribute__((ext_vector_type(4))) float  f32x4;
typedef __attribute__((ext_vector_type(8))) __bf16 bf16x8;
typedef __attribute__((ext_vector_type(4))) unsigned int u32x4;

__device__ __forceinline__ unsigned short f2bu(float x) {
    __bf16 h = (__bf16)x;
    return __builtin_bit_cast(unsigned short, h);
}

__device__ __forceinline__ f32x4 MF(bf16x8 a, bf16x8 b, f32x4 c) {
    return __builtin_amdgcn_mfma_f32_16x16x32_bf16(a, b, c, 0, 0, 0);
}

__device__ __forceinline__ f32x4 zero4() { f32x4 z = {0.f, 0.f, 0.f, 0.f}; return z; }

// B-fragment (BT row-major, contiguous K): lane holds BT[row][k0..k0+7], f32 -> bf16
__device__ __forceinline__ bf16x8 bfrag_g(const float* W, int ldk, int row, int k0) {
    const float* p = W + (size_t)row * ldk + k0;
    bf16x8 r;
#pragma unroll
    for (int e = 0; e < 8; ++e) r[e] = (__bf16)p[e];
    return r;
}

// ---- LDS layout (bytes), M=16 atoms/tile, two ping-pong sets ----
// per set: VIN 3*16*256 = 12288 ; H 16*512 = 8192  -> SET_SZ 20480
#define SET_SZ   20480
#define VIN_OFF  0
#define H_OFF    12288
#define S1_OFF   40960   // single shared S1: 16*256 = 4096
#define RED_OFF  45056   // 8 waves * 16 f32 = 512
#define LDS_BYTES 45568

// A-fragment read from swizzled LDS tile
__device__ __forceinline__ bf16x8 afrag(const unsigned char* base, int rb, int row, int kb) {
    u32x4 q = *(const u32x4*)(base + row * rb + (kb ^ ((row & 7) << 4)));
    return __builtin_bit_cast(bf16x8, q);
}

__device__ __forceinline__ unsigned long long pack4bf(f32x4 x) {
    return (unsigned long long)f2bu(x[0])
         | ((unsigned long long)f2bu(x[1]) << 16)
         | ((unsigned long long)f2bu(x[2]) << 32)
         | ((unsigned long long)f2bu(x[3]) << 48);
}

__global__ __launch_bounds__(512, 2) void eqsc_main(
    const float* __restrict__ S, const float* __restrict__ V,
    const float* __restrict__ u0w, const float* __restrict__ v0w,
    const float* __restrict__ a0w1, const float* __restrict__ a0b1,
    const float* __restrict__ a0w2, const float* __restrict__ a0b2,
    const float* __restrict__ u1w, const float* __restrict__ v1w,
    const float* __restrict__ a1w1, const float* __restrict__ a1b1,
    const float* __restrict__ a1w2, const float* __restrict__ a1b2,
    const float* __restrict__ outw, const float* __restrict__ outbp,
    float* __restrict__ sOut, int NT)
{
    __shared__ __align__(16) unsigned char lds[LDS_BYTES];
    const int tid  = threadIdx.x;
    const int lane = tid & 63;
    const int wv   = tid >> 6;
    const int l15  = lane & 15;
    const int lg   = lane >> 4;
    const int grow = wv * 16 + l15;   // this wave/lane's output feature column
    const int kbb  = lg << 4;         // k-byte base within a 64B kt chunk

    // ---- folded readout: wfold[k] = sum_g a1w2[g,k]*outw[g]; cfold = b2g1.outw + outb
    float wf = 0.f, cf = 0.f;
    for (int g = 0; g < 128; ++g) {
        float og = outw[g];
        wf += a1w2[g * 128 + grow] * og;
        cf += a1b2[g] * og;
    }
    cf += outbp[0];

    // ---- persistent weight fragments (bf16, register-resident): 144 VGPRs ----
    bf16x8 uw0f[4], vw0f[4], w2g0[4], w2s0[4], vw1f[4];
    bf16x8 w1f0[8], w1f1[8];
#pragma unroll
    for (int kt = 0; kt < 4; ++kt) {
        int k0 = kt * 32 + lg * 8;
        uw0f[kt] = bfrag_g(u0w, 128, grow, k0);
        vw0f[kt] = bfrag_g(v0w, 128, grow, k0);
        w2g0[kt] = bfrag_g(a0w2, 128, grow, k0);
        w2s0[kt] = bfrag_g(a0w2, 128, 128 + grow, k0);
        vw1f[kt] = bfrag_g(v1w, 128, grow, k0);
    }
#pragma unroll
    for (int kt = 0; kt < 8; ++kt) {
        int k0 = kt * 32 + lg * 8;
        w1f0[kt] = bfrag_g(a0w1, 256, grow, k0);
        w1f1[kt] = bfrag_g(a1w1, 256, grow, k0);
    }
    const float b1_0 = a0b1[grow];
    const float b2g0 = a0b2[grow];
    const float b2s0 = a0b2[128 + grow];
    const float b1_1 = a1b1[grow];

    const int stride = gridDim.x;
    const int t0 = blockIdx.x;

    // ---- prologue: stage tile t0 into set 0 ----
    {
        f32x4 vld[3], sld;
#pragma unroll
        for (int j = 0; j < 3; ++j) {
            int c = tid + (j << 9);
            int d = c >> 9, rem = c & 511;
            int row = rem >> 5, c4 = rem & 31;
            vld[j] = *(const f32x4*)(V + (((size_t)((t0 << 4) + row) * 3 + d) << 7) + (c4 << 2));
        }
        { int row = tid >> 5, c4 = tid & 31;
          sld = *(const f32x4*)(S + (((size_t)((t0 << 4) + row)) << 7) + (c4 << 2)); }
#pragma unroll
        for (int j = 0; j < 3; ++j) {
            int c = tid + (j << 9);
            int d = c >> 9, rem = c & 511;
            int row = rem >> 5, c4 = rem & 31;
            *(unsigned long long*)(lds + VIN_OFF + (d << 12) + row * 256 +
                                   ((c4 << 3) ^ ((row & 7) << 4))) = pack4bf(vld[j]);
        }
        { int row = tid >> 5, c4 = tid & 31;
          *(unsigned long long*)(lds + H_OFF + row * 512 +
                                 ((c4 << 3) ^ ((row & 7) << 4))) = pack4bf(sld); }
    }
    __syncthreads();

    int i = 0;
    for (int ty = t0; ty < NT + stride; ty += stride, ++i) {
        const bool yv = (ty < NT);
        const bool xv = (i > 0);
        const int  tz = ty + stride;
        const bool zv = (tz < NT);
        unsigned char* Lsy = lds + (i & 1) * SET_SZ;
        unsigned char* Lsx = lds + ((i & 1) ^ 1) * SET_SZ;

        // ======== slot 1: Y.P1 (L0 v-phase) || X.P4 (L1 v-phase) ; issue Z loads ========
        f32x4 vld[3], sld;
        if (zv) {
#pragma unroll
            for (int j = 0; j < 3; ++j) {
                int c = tid + (j << 9);
                int d = c >> 9, rem = c & 511;
                int row = rem >> 5, c4 = rem & 31;
                vld[j] = *(const f32x4*)(V + (((size_t)((tz << 4) + row) * 3 + d) << 7) + (c4 << 2));
            }
            { int row = tid >> 5, c4 = tid & 31;
              sld = *(const f32x4*)(S + (((size_t)((tz << 4) + row)) << 7) + (c4 << 2)); }
        }

        f32x4 v1a[3];
        if (yv) {
            f32x4 n2 = zero4();
#pragma unroll
            for (int d = 0; d < 3; ++d) {
                f32x4 a1 = zero4(), a2 = zero4();
#pragma unroll
                for (int kt = 0; kt < 4; ++kt) {
                    bf16x8 a = afrag(Lsy + VIN_OFF + (d << 12), 256, l15, (kt << 6) + kbb);
                    a1 = MF(a, uw0f[kt], a1);
                    a2 = MF(a, vw0f[kt], a2);
                }
                v1a[d] = a1;
#pragma unroll
                for (int e = 0; e < 4; ++e) { float x = a2[e] + 1e-8f; n2[e] += x * x; }
            }
#pragma unroll
            for (int e = 0; e < 4; ++e) {
                int row = (lg << 2) + e;
                *(unsigned short*)(Lsy + H_OFF + row * 512 +
                    ((256 + (grow << 1)) ^ ((row & 7) << 4))) = f2bu(sqrtf(n2[e]));
            }
        }
        if (xv) {
            f32x4 n2 = zero4();
#pragma unroll
            for (int d = 0; d < 3; ++d) {
                f32x4 acc = zero4();
#pragma unroll
                for (int kt = 0; kt < 4; ++kt)
                    acc = MF(afrag(Lsx + VIN_OFF + (d << 12), 256, l15, (kt << 6) + kbb),
                             vw1f[kt], acc);
#pragma unroll
                for (int e = 0; e < 4; ++e) { float x = acc[e] + 1e-8f; n2[e] += x * x; }
            }
#pragma unroll
            for (int e = 0; e < 4; ++e) {
                int row = (lg << 2) + e;
                *(unsigned short*)(Lsx + H_OFF + row * 512 +
                    ((256 + (grow << 1)) ^ ((row & 7) << 4))) = f2bu(sqrtf(n2[e]));
            }
        }
        __syncthreads();

        // ======== slot 2: Y.P2 (L0 MLP1) || X.P5 (L1 MLP1 + folded readout) ; write V(Z) ========
        if (yv) {
            f32x4 m = zero4();
#pragma unroll
            for (int kt = 0; kt < 8; ++kt)
                m = MF(afrag(Lsy + H_OFF, 512, l15, (kt << 6) + kbb), w1f0[kt], m);
#pragma unroll
            for (int e = 0; e < 4; ++e) {
                float x = m[e] + b1_0;
                float y = x / (1.f + __expf(-x));
                int row = (lg << 2) + e;
                *(unsigned short*)(lds + S1_OFF + row * 256 +
                    ((grow << 1) ^ ((row & 7) << 4))) = f2bu(y);
            }
        }
        if (xv) {
            f32x4 m = zero4();
#pragma unroll
            for (int kt = 0; kt < 8; ++kt)
                m = MF(afrag(Lsx + H_OFF, 512, l15, (kt << 6) + kbb), w1f1[kt], m);
            float p[4];
#pragma unroll
            for (int e = 0; e < 4; ++e) {
                float x = m[e] + b1_1;
                float y = x / (1.f + __expf(-x));
                p[e] = y * wf;                    // folded (w2g1^T @ outw) readout, f32
            }
#pragma unroll
            for (int off = 1; off < 16; off <<= 1) {
#pragma unroll
                for (int e = 0; e < 4; ++e) p[e] += __shfl_xor(p[e], off);
            }
            if (l15 == 0) {
#pragma unroll
                for (int e = 0; e < 4; ++e)
                    *((float*)(lds + RED_OFF) + (wv << 4) + (lg << 2) + e) = p[e];
            }
        }
        if (zv) {
#pragma unroll
            for (int j = 0; j < 3; ++j) {
                int c = tid + (j << 9);
                int d = c >> 9, rem = c & 511;
                int row = rem >> 5, c4 = rem & 31;
                *(unsigned long long*)(Lsx + VIN_OFF + (d << 12) + row * 256 +
                                       ((c4 << 3) ^ ((row & 7) << 4))) = pack4bf(vld[j]);
            }
        }
        __syncthreads();

        // ======== slot 3: Y.P3 (L0 MLP2 + v'=v1*ss) ; write S(Z) ; sOut(X) ========
        if (yv) {
            f32x4 sg = zero4(), ssa = zero4();
#pragma unroll
            for (int kt = 0; kt < 4; ++kt) {
                bf16x8 a = afrag(lds + S1_OFF, 256, l15, (kt << 6) + kbb);
                sg  = MF(a, w2g0[kt], sg);
                ssa = MF(a, w2s0[kt], ssa);
            }
#pragma unroll
            for (int e = 0; e < 4; ++e) {
                int row = (lg << 2) + e;
                int swz = (row & 7) << 4;
                *(unsigned short*)(Lsy + H_OFF + row * 512 + ((grow << 1) ^ swz)) = f2bu(sg[e] + b2g0);
                float ssv = ssa[e] + b2s0;
#pragma unroll
                for (int d = 0; d < 3; ++d)
                    *(unsigned short*)(Lsy + VIN_OFF + (d << 12) + row * 256 +
                        ((grow << 1) ^ swz)) = f2bu(v1a[d][e] * ssv);
            }
        }
        if (zv) {
            int row = tid >> 5, c4 = tid & 31;
            *(unsigned long long*)(Lsx + H_OFF + row * 512 +
                                   ((c4 << 3) ^ ((row & 7) << 4))) = pack4bf(sld);
        }
        if (xv && tid < 16) {
            float s = 0.f;
#pragma unroll
            for (int w = 0; w < 8; ++w) s += *((float*)(lds + RED_OFF) + (w << 4) + tid);
            sOut[((ty - stride) << 4) + tid] = s + cf;
        }
        __syncthreads();
    }
}

// Dense masked pooling: y[b] = sum_a batch[b,a] * s_out[a]
__global__ __launch_bounds__(256) void eqsc_pool(const float* __restrict__ batch,
                                                 const float* __restrict__ s,
                                                 float* __restrict__ out,
                                                 int NA, int B, int CH)
{
    int b  = blockIdx.x % B;
    int ch = blockIdx.x / B;
    int a0 = ch * CH;
    int a1 = min(a0 + CH, NA);
    const float* br = batch + (size_t)b * NA;
    float acc = 0.f;
    for (int a = a0 + (threadIdx.x << 2); a < a1; a += 256 * 4) {
        f32x4 bb = *(const f32x4*)(br + a);
        f32x4 sv = *(const f32x4*)(s + a);
        acc += bb[0] * sv[0] + bb[1] * sv[1] + bb[2] * sv[2] + bb[3] * sv[3];
    }
#pragma unroll
    for (int off = 32; off > 0; off >>= 1) acc += __shfl_down(acc, off);
    __shared__ float wsum[4];
    if ((threadIdx.x & 63) == 0) wsum[threadIdx.x >> 6] = acc;
    __syncthreads();
    if (threadIdx.x == 0) atomicAdd(&out[b], wsum[0] + wsum[1] + wsum[2] + wsum[3]);
}

extern "C" void kernel_launch(void* const* d_in, const int* in_sizes, int n_in,
                              void* d_out, int out_size, void* d_ws, size_t ws_size,
                              hipStream_t stream)
{
    const float* S     = (const float*)d_in[0];
    const float* V     = (const float*)d_in[1];
    // d_in[2] = pos, unused by the reference
    const float* batch = (const float*)d_in[3];
    const float* u0w   = (const float*)d_in[4];
    const float* v0w   = (const float*)d_in[5];
    const float* a0w1  = (const float*)d_in[6];
    const float* a0b1  = (const float*)d_in[7];
    const float* a0w2  = (const float*)d_in[8];
    const float* a0b2  = (const float*)d_in[9];
    const float* u1w   = (const float*)d_in[10];
    const float* v1w   = (const float*)d_in[11];
    const float* a1w1  = (const float*)d_in[12];
    const float* a1b1  = (const float*)d_in[13];
    const float* a1w2  = (const float*)d_in[14];
    const float* a1b2  = (const float*)d_in[15];
    const float* outw  = (const float*)d_in[16];
    const float* outb  = (const float*)d_in[17];

    const int NA = in_sizes[0] / 128;
    const int NT = NA / 16;                  // 16 atoms per tile
    const int B  = in_sizes[3] / NA;
    float* sAtom = (float*)d_ws;

    hipMemsetAsync(d_out, 0, (size_t)out_size * sizeof(float), stream);

    eqsc_main<<<256, 512, 0, stream>>>(S, V, u0w, v0w, a0w1, a0b1, a0w2, a0b2,
                                       u1w, v1w, a1w1, a1b1, a1w2, a1b2,
                                       outw, outb, sAtom, NT);

    const int CH  = 16384;
    const int NCH = (NA + CH - 1) / CH;
    eqsc_pool<<<B * NCH, 256, 0, stream>>>(batch, sAtom, (float*)d_out, NA, B, CH);
}